// Round 3
// baseline (416.710 us; speedup 1.0000x reference)
//
#include <hip/hip_runtime.h>
#include <cstdint>

#define NCOLS  696     // 16 + 120 + 560 subsets of size <= 3, bitmask order
#define NGROUP 174     // NCOLS / 4
#define NREC   136     // 16 singles + 120 pairs
#define WPB    4       // waves per block
#define RPW    8       // rows per wave (amortize end-of-wave store drain)
#define BLOCK  256

typedef float v4f __attribute__((ext_vector_type(4)));

// Record id: single a -> a ; pair (a<b) -> 16 + b*(b-1)/2 + a.
constexpr int pr(int a, int b) { return 16 + b * (b - 1) / 2 + a; }

// Per-record source operands (lo | hi<<8): rec[r] = selpair(v[hi], v[lo]).
struct alignas(8) RecSrc { uint16_t d[NREC]; };
constexpr RecSrc make_recs() {
    RecSrc t{};
    for (int a = 0; a < 16; ++a) t.d[a] = (uint16_t)(a | (a << 8));
    int p = 16;
    for (int b = 1; b < 16; ++b)
        for (int a = 0; a < b; ++a)
            t.d[p++] = (uint16_t)(a | (b << 8));
    return t;
}

// Per-column descriptor (Lrec | Rrec<<8): out = selpair(rec[Lrec], rec[Rrec]).
struct alignas(8) ColTbl { uint16_t d[NCOLS]; };
constexpr ColTbl make_cols() {
    ColTbl t{};
    int p = 0;
    for (int h = 0; h < 16; ++h) {
        t.d[p++] = (uint16_t)(h | (h << 8));
        for (int j = 0; j < h; ++j) {
            int pjh = pr(j, h);
            t.d[p++] = (uint16_t)(pjh | (pjh << 8));
            for (int i = 0; i < j; ++i)
                t.d[p++] = (uint16_t)(pr(j, h) | (pr(i, j) << 8));
        }
    }
    return t;
}

__constant__ RecSrc g_recs = make_recs();
__constant__ ColTbl g_cols = make_cols();

// Tie-exact select. cur comparison uses the sum proxy: RN(0.5l+0.5u) =
// 0.5*RN(l+u) exactly (power-of-two scaling), so ==/> are preserved
// bit-for-bit vs the NumPy fp32 reference. Beta path kept in RN form.
__device__ __forceinline__ float2 selpair(float2 L, float2 R) {
    float curL = __fadd_rn(L.x, L.y);
    float curR = __fadd_rn(R.x, R.y);
    float bL = __fadd_rn(__fmul_rn(0.2f, L.x), __fmul_rn(0.8f, L.y));
    float bR = __fadd_rn(__fmul_rn(0.2f, R.x), __fmul_rn(0.8f, R.y));
    bool choose_right = (curL == curR) ? (bL > bR) : (curL > curR);
    return choose_right ? R : L;
}

__device__ __forceinline__ float2 col_compute(const float2* __restrict__ rec,
                                              uint32_t d) {
    float2 L = rec[d & 255u];
    float2 R = rec[(d >> 8) & 255u];
    return selpair(L, R);
}

// 2048 blocks x 8 blocks/CU = 32 waves/CU; each wave owns 8 consecutive rows
// and loops over them with no block barriers, so row k+1's LDS/VALU work
// runs underneath row k's in-flight stores (fire-and-forget; drain only at
// s_endpgm, amortized 8x). This breaks the one-row-per-wave convoy where
// all resident waves hit their store burst simultaneously.
__global__ __launch_bounds__(BLOCK, 8) void minint_kernel(
    const float* __restrict__ xl, const float* __restrict__ xu,
    float* __restrict__ out, int batch)
{
    __shared__ float2 vals[WPB][16];
    __shared__ float2 recs[WPB][NREC];
    const int t    = threadIdx.x;
    const int w    = t >> 6;
    const int lane = t & 63;
    const int row0 = (blockIdx.x * WPB + w) * RPW;

    // ---- Loop-invariant descriptor preload (vmcnt-counted loads hoisted
    // out of the row loop entirely). Clamped duplicates keep lanes valid.
    const ushort4* colsp = (const ushort4*)g_cols.d;
    const ushort4 d0 = colsp[lane];
    const ushort4 d1 = colsp[lane + 64];
    const bool has3  = lane < (NGROUP - 128);            // lanes 0..45
    const ushort4 d2 = colsp[has3 ? lane + 128 : lane];
    const uint32_t s0 = g_recs.d[lane];
    const uint32_t s1 = g_recs.d[lane + 64];
    const bool hasR2  = lane < (NREC - 128);             // lanes 0..7
    const uint32_t s2 = g_recs.d[hasR2 ? lane + 128 : lane];

    // Row-input fetch: lanes 0-15 carry xl[row][i], lanes 16-31 xu[row][i].
    const bool ldact = lane < 32;
    const float* srcp = (lane < 16) ? xl : xu;
    const int    lidx = lane & 15;
    float* const vp   = (float*)vals[w];   // vp[i*2+0]=l_i, vp[i*2+1]=u_i

    // Prefetch row 0 of this wave.
    float pref = ldact ? srcp[(row0)*16 + lidx] : 0.0f;

    for (int k = 0; k < RPW; ++k) {
        const int row = row0 + k;

        // Stage prefetched row into LDS (wave-private; DS pipe is in-order
        // per wave, so reuse of vals/recs across k needs no barriers —
        // wave_barrier only pins code motion at phase edges).
        if (ldact) vp[lidx * 2 + (lane >> 4)] = pref;
        __builtin_amdgcn_wave_barrier();

        // Prefetch next row immediately: its vmcnt latency hides under the
        // rec + col compute of the current row.
        if (k + 1 < RPW && ldact) pref = srcp[(row + 1) * 16 + lidx];

        // ---- 136 single/pair records for this row ----
        const float2* v = vals[w];
        {
            float2 lo = v[s0 & 15u], hi = v[(s0 >> 8) & 15u];
            recs[w][lane] = selpair(hi, lo);
            lo = v[s1 & 15u]; hi = v[(s1 >> 8) & 15u];
            recs[w][lane + 64] = selpair(hi, lo);
            if (hasR2) {
                lo = v[s2 & 15u]; hi = v[(s2 >> 8) & 15u];
                recs[w][lane + 128] = selpair(hi, lo);
            }
        }
        __builtin_amdgcn_wave_barrier();

        // ---- Column phase: 174 groups of 4 cols; stores fire-and-forget.
        // Row byte stride = 696*4 = 174*16 -> float4 stores stay 16B-aligned.
        const float2* rec = recs[w];
        float* outl = out + (size_t)row * NCOLS;
        float* outu = out + (size_t)batch * NCOLS + (size_t)row * NCOLS;

#define DO_GROUP(gi, dd) do {                                        \
        float2 c0 = col_compute(rec, (dd).x);                        \
        float2 c1 = col_compute(rec, (dd).y);                        \
        float2 c2 = col_compute(rec, (dd).z);                        \
        float2 c3 = col_compute(rec, (dd).w);                        \
        v4f rl = { c0.x, c1.x, c2.x, c3.x };                         \
        v4f ru = { c0.y, c1.y, c2.y, c3.y };                         \
        *(v4f*)(outl + 4 * (gi)) = rl;                               \
        *(v4f*)(outu + 4 * (gi)) = ru;                               \
    } while (0)

        DO_GROUP(lane,       d0);
        DO_GROUP(lane + 64,  d1);
        if (has3) DO_GROUP(lane + 128, d2);
#undef DO_GROUP
        __builtin_amdgcn_wave_barrier();
    }
}

extern "C" void kernel_launch(void* const* d_in, const int* in_sizes, int n_in,
                              void* d_out, int out_size, void* d_ws, size_t ws_size,
                              hipStream_t stream) {
    const float* xl = (const float*)d_in[0];
    const float* xu = (const float*)d_in[1];
    float* out = (float*)d_out;
    const int batch = in_sizes[0] / 16;          // 65536
    const int grid  = batch / (WPB * RPW);       // 2048 blocks x 4 waves x 8 rows
    minint_kernel<<<grid, BLOCK, 0, stream>>>(xl, xu, out, batch);
}